// Round 6
// baseline (187.400 us; speedup 1.0000x reference)
//
#include <hip/hip_runtime.h>

typedef short s16x8 __attribute__((ext_vector_type(8)));
typedef float f32x4 __attribute__((ext_vector_type(4)));
typedef unsigned int u32x2 __attribute__((ext_vector_type(2)));
typedef unsigned short u16;
typedef unsigned int u32;

#define D_MODEL 1024
#define NHEAD   16
#define HD      64
#define TSEQ    2048
#define NB      2
#define MROWS   4096   // B*T
#define NSPLIT  2
#define NTILES  (TSEQ / 64 / NSPLIT)   // 16 kv tiles per split

#define LOG2E 1.4426950408889634f
#define QSCALE (0.125f * LOG2E)   // folded into Q projection epilogue

__device__ __forceinline__ u16 f2bf(float f) {
  unsigned u = __builtin_bit_cast(unsigned, f);
  u += 0x7fffu + ((u >> 16) & 1u);
  return (u16)(u >> 16);
}

__device__ __forceinline__ float bf2f(u16 x) {
  return __builtin_bit_cast(float, (u32)x << 16);
}

__device__ __forceinline__ u32 cvtpk(float lo, float hi) {
  u32 r;
  asm("v_cvt_pk_bf16_f32 %0, %1, %2" : "=v"(r) : "v"(lo), "v"(hi));
  return r;
}

__device__ __forceinline__ float exp2fast(float x) {
#if __has_builtin(__builtin_amdgcn_exp2f)
  return __builtin_amdgcn_exp2f(x);
#else
  return exp2f(x);
#endif
}

__device__ __forceinline__ float rcpfast(float x) {
#if __has_builtin(__builtin_amdgcn_rcpf)
  return __builtin_amdgcn_rcpf(x);
#else
  return 1.f / x;
#endif
}

__device__ __forceinline__ void gload16(const void* g, void* l) {
  __builtin_amdgcn_global_load_lds((const __attribute__((address_space(1))) void*)g,
                                   (__attribute__((address_space(3))) void*)l,
                                   16, 0, 0);
}

// ---------------- fused fp32->bf16 converts + bias_sum (one dispatch) ----------------
__global__ void cvt_all(const float* __restrict__ q, const float* __restrict__ k,
                        const float* __restrict__ v, const float* __restrict__ wq,
                        const float* __restrict__ wk, const float* __restrict__ wv,
                        const float* __restrict__ wo, const float* __restrict__ ab,
                        u16* qb, u16* kb, u16* vb, u16* wqb, u16* wkb, u16* wvb, u16* wob,
                        float* bsum) {
  if (blockIdx.x == 16384) {
    if (threadIdx.x < 64) {
      float s = ab[threadIdx.x];
#pragma unroll
      for (int m = 32; m >= 1; m >>= 1) s += __shfl_xor(s, m);
      if (threadIdx.x == 0) bsum[0] = s * 0.125f * LOG2E;  // pre-fold scale*log2e
    }
    return;
  }
  int i = blockIdx.x * 256 + threadIdx.x;   // float4 index
  const float* src; u16* dst; int off;
  if (i < 3 * 1048576) {
    int t = i >> 20; off = i & 1048575;
    src = (t == 0) ? q : (t == 1) ? k : v;
    dst = (t == 0) ? qb : (t == 1) ? kb : vb;
  } else {
    int j = i - 3 * 1048576;
    int t = j >> 18; off = j & 262143;
    src = (t == 0) ? wq : (t == 1) ? wk : (t == 2) ? wv : wo;
    dst = (t == 0) ? wqb : (t == 1) ? wkb : (t == 2) ? wvb : wob;
  }
  float4 x = ((const float4*)src)[off];
  ushort4 o;
  o.x = f2bf(x.x); o.y = f2bf(x.y); o.z = f2bf(x.z); o.w = f2bf(x.w);
  ((ushort4*)dst)[off] = o;
}

// ---------------- double-buffered GEMM core: C = (A*Bt^T + bias)*oscale ----------------
template <int BM, int BN, int WN>
__device__ __forceinline__ void gemm_core(const u16* __restrict__ A, const u16* __restrict__ Bt,
                                          const float* __restrict__ bias, void* __restrict__ out,
                                          float oscale, int mode, u16* lds) {
  constexpr int K = 1024, N = 1024;
  constexpr int WM = 4 / WN;
  constexpr int WTM = BM / WM, WTN = BN / WN;
  constexpr int MR = WTM / 16, NR = WTN / 16;
  constexpr int ASZ = BM * 32, BSZ = BN * 32;
  constexpr int AISS = ASZ / 2048, BISS = BSZ / 2048;
  u16* lA = lds;
  u16* lB = lds + 2 * ASZ;

  const int tid = threadIdx.x;
  const int wid = tid >> 6, lane = tid & 63;
  const int l15 = lane & 15, lgp = lane >> 4;
  const int wr = wid / WN, wc = wid % WN;
  const int m0 = blockIdx.y * BM, n0 = blockIdx.x * BN;

  const u16* gA[AISS];
  const u16* gB[BISS];
#pragma unroll
  for (int i = 0; i < AISS; ++i) {
    int tp = i * 256 + tid, row = tp % BM, kc = tp / BM;
    gA[i] = A + (size_t)(m0 + row) * K + kc * 8;
  }
#pragma unroll
  for (int i = 0; i < BISS; ++i) {
    int tp = i * 256 + tid, row = tp % BN, kc = tp / BN;
    gB[i] = Bt + (size_t)(n0 + row) * K + kc * 8;
  }

  f32x4 acc[MR][NR];
#pragma unroll
  for (int m = 0; m < MR; ++m)
#pragma unroll
    for (int n = 0; n < NR; ++n) acc[m][n] = (f32x4){0.f, 0.f, 0.f, 0.f};

  auto stage = [&](int buf, int k0) {
#pragma unroll
    for (int i = 0; i < AISS; ++i)
      gload16(gA[i] + k0, lA + buf * ASZ + (i * 256 + tid) * 8);
#pragma unroll
    for (int i = 0; i < BISS; ++i)
      gload16(gB[i] + k0, lB + buf * BSZ + (i * 256 + tid) * 8);
  };

  int cur = 0;
  stage(0, 0);
  __syncthreads();
  for (int k0 = 0; k0 < K; k0 += 32) {
    if (k0 + 32 < K) stage(cur ^ 1, k0 + 32);
    const u16* a = lA + cur * ASZ;
    const u16* b = lB + cur * BSZ;
    s16x8 af[MR], bf[NR];
#pragma unroll
    for (int m = 0; m < MR; ++m)
      af[m] = *(const s16x8*)(a + lgp * BM * 8 + (wr * WTM + m * 16 + l15) * 8);
#pragma unroll
    for (int n = 0; n < NR; ++n)
      bf[n] = *(const s16x8*)(b + lgp * BN * 8 + (wc * WTN + n * 16 + l15) * 8);
    __builtin_amdgcn_s_setprio(1);
#pragma unroll
    for (int m = 0; m < MR; ++m)
#pragma unroll
      for (int n = 0; n < NR; ++n)
        acc[m][n] = __builtin_amdgcn_mfma_f32_16x16x32_bf16(af[m], bf[n], acc[m][n], 0, 0, 0);
    __builtin_amdgcn_s_setprio(0);
    __syncthreads();
    cur ^= 1;
  }

  float bvv[NR];
#pragma unroll
  for (int n = 0; n < NR; ++n) bvv[n] = bias[n0 + wc * WTN + n * 16 + l15];

#pragma unroll
  for (int m = 0; m < MR; ++m) {
    int rowb = m0 + wr * WTM + m * 16 + lgp * 4;
#pragma unroll
    for (int n = 0; n < NR; ++n) {
      int col = n0 + wc * WTN + n * 16 + l15;
#pragma unroll
      for (int r = 0; r < 4; ++r) {
        int row = rowb + r;
        float vv = (acc[m][n][r] + bvv[n]) * oscale;
        if (mode == 2) {
          ((float*)out)[(size_t)row * N + col] = vv;
        } else {
          int b = row >> 11, t = row & 2047;
          int h = col >> 6, d = col & 63;
          u16 x = f2bf(vv);
          if (mode == 0)
            ((u16*)out)[(((size_t)(b * NHEAD + h) * TSEQ + t) << 6) + d] = x;
          else
            ((u16*)out)[(((size_t)(b * NHEAD + h) * HD + d) << 11) + t] = x;
        }
      }
    }
  }
}

__global__ __launch_bounds__(256) void gemm_qkv(const u16* __restrict__ qb, const u16* __restrict__ kb,
                                                const u16* __restrict__ vb,
                                                const u16* __restrict__ Wqb, const u16* __restrict__ Wkb,
                                                const u16* __restrict__ Wvb,
                                                const float* __restrict__ bq, const float* __restrict__ bk,
                                                const float* __restrict__ bv,
                                                u16* Qp, u16* Kp, u16* Vtp) {
  __shared__ __align__(16) u16 lds[2 * 128 * 32 * 2];   // 32 KB
  int z = blockIdx.z;
  const u16* A  = (z == 0) ? qb : (z == 1) ? kb : vb;
  const u16* Bt = (z == 0) ? Wqb : (z == 1) ? Wkb : Wvb;
  const float* bias = (z == 0) ? bq : (z == 1) ? bk : bv;
  u16* out = (z == 0) ? Qp : (z == 1) ? Kp : Vtp;
  int mode = (z == 2) ? 1 : 0;
  float oscale = (z == 0) ? QSCALE : 1.0f;
  gemm_core<128, 128, 2>(A, Bt, bias, out, oscale, mode, lds);
}

__global__ __launch_bounds__(256) void gemm_out(const u16* __restrict__ A, const u16* __restrict__ Bt,
                                                const float* __restrict__ bias, float* __restrict__ out) {
  __shared__ __align__(16) u16 lds[2 * 64 * 32 + 2 * 128 * 32];   // 24 KB
  gemm_core<64, 128, 4>(A, Bt, bias, out, 1.0f, 2, lds);
}

// ---------------- flash attention, kv-split x2, 32KB LDS (5 blocks/CU) ----------------
// grid: (T/64, B*H, NSPLIT), block 256 = 4 waves. Wave w owns 16 q rows.
// K single-buffered (8KB), V double (16KB), per-wave plds (8KB). 2 barriers/tile:
//   read K-frags -> sync1 -> stage K(t+1),V(t+1) -> QK -> softmax -> PV(vbuf[cur]) -> sync2
// Outputs UNNORMALIZED partial O (bf16) + per-row (m2, lsum) for the combine pass.
__global__ __launch_bounds__(256, 4) void attn_kernel(const u16* __restrict__ Qp,
                                                      const u16* __restrict__ Kp,
                                                      const u16* __restrict__ Vt,
                                                      const float* __restrict__ frac,
                                                      const float* __restrict__ bsum,
                                                      u16* __restrict__ o0,
                                                      u16* __restrict__ o1,
                                                      float2* __restrict__ ml) {
  __shared__ __align__(16) u16 kbuf[64 * 64];       // 8 KB (single-buffered)
  __shared__ __align__(16) u16 vbuf[2][64 * 64];    // 16 KB
  __shared__ __align__(16) u16 plds[4][16 * 64];    // 8 KB
  const int tid = threadIdx.x, wid = tid >> 6, lane = tid & 63;
  const int l15 = lane & 15, lgp = lane >> 4;
  const int bh = blockIdx.y, b = bh >> 4, h = bh & 15;
  const int z = blockIdx.z;
  const int kvbase = z * (TSEQ / NSPLIT);
  u16* opart = z ? o1 : o0;
  float2* mlz = ml + z * (NB * NHEAD * TSEQ);
  const u16* Qh = Qp + (size_t)bh * TSEQ * HD;
  const u16* Kh = Kp + (size_t)bh * TSEQ * HD;
  const u16* Vh = Vt + (size_t)bh * HD * TSEQ;
  const float* fb = frac + b * TSEQ;
  const float bs = bsum[0];                    // bias_sum * scale * log2e (pre-folded)
  const float THR2 = 24.0f;
  const int q0 = blockIdx.x * 64 + wid * 16;

  // staging lane constants (pre-swizzled global source, rule #21)
  const int srow = lane >> 3;
  const int sg8 = ((lane & 7) ^ srow) * 8;
  const int rbase = wid * 8 + srow;

  // frag-read offsets (u16 units)
  const int ofs0 = l15 * 64 + ((lgp ^ (l15 & 7)) * 8);
  const int ofs1 = l15 * 64 + (((4 + lgp) ^ (l15 & 7)) * 8);

  // Q fragments (B-operand: lane l15 = q col, lgp*8 = dh slice)
  s16x8 qf[2];
#pragma unroll
  for (int ks = 0; ks < 2; ++ks)
    qf[ks] = *(const s16x8*)(Qh + (size_t)(q0 + l15) * HD + ks * 32 + lgp * 8);

  const float fi = fb[q0 + l15];
  const float nbfi = -bs * fi;
  float m2run = -1e30f;
  float lsum = 0.f;
  f32x4 o[4];
#pragma unroll
  for (int nd = 0; nd < 4; ++nd) o[nd] = (f32x4){0.f, 0.f, 0.f, 0.f};

  auto stageK = [&](int t) {
    int kv0s = kvbase + t * 64;
#pragma unroll
    for (int i = 0; i < 2; ++i)
      gload16(Kh + (size_t)(kv0s + i * 32 + rbase) * HD + sg8, &kbuf[i * 2048 + wid * 512]);
  };
  auto stageV = [&](int buf, int t) {
    int kv0s = kvbase + t * 64;
#pragma unroll
    for (int i = 0; i < 2; ++i)
      gload16(Vh + (size_t)(i * 32 + rbase) * TSEQ + kv0s + sg8, &vbuf[buf][i * 2048 + wid * 512]);
  };

  int cur = 0;
  stageK(0);
  stageV(0, 0);
  __syncthreads();

  for (int t = 0; t < NTILES; ++t) {
    // ---- grab K fragments from kbuf into registers
    s16x8 kf[4][2];
#pragma unroll
    for (int n = 0; n < 4; ++n) {
      kf[n][0] = *(const s16x8*)(&kbuf[0] + n * 1024 + ofs0);
      kf[n][1] = *(const s16x8*)(&kbuf[0] + n * 1024 + ofs1);
    }
    float4 fj4[4];
#pragma unroll
    for (int n = 0; n < 4; ++n)
      fj4[n] = *(const float4*)(fb + kvbase + t * 64 + n * 16 + lgp * 4);

    __syncthreads();   // sync1: all waves done reading kbuf
    if (t + 1 < NTILES) { stageK(t + 1); stageV(cur ^ 1, t + 1); }

    // ---- QK^T (swapped): s[n][r] = S_log2[kv][q0+l15]
    f32x4 s[4];
    __builtin_amdgcn_s_setprio(1);
#pragma unroll
    for (int n = 0; n < 4; ++n) {
      f32x4 a = (f32x4){0.f, 0.f, 0.f, 0.f};
      a = __builtin_amdgcn_mfma_f32_16x16x32_bf16(kf[n][0], qf[0], a, 0, 0, 0);
      a = __builtin_amdgcn_mfma_f32_16x16x32_bf16(kf[n][1], qf[1], a, 0, 0, 0);
      s[n] = a;
    }
    __builtin_amdgcn_s_setprio(0);

    // ---- logits (log2 domain): l2 = s + bs*(fj-fi)/(fi*fj+eps)
    float pmax = -1e30f;
#pragma unroll
    for (int n = 0; n < 4; ++n) {
#pragma unroll
      for (int r = 0; r < 4; ++r) {
        float fj = (r == 0) ? fj4[n].x : (r == 1) ? fj4[n].y : (r == 2) ? fj4[n].z : fj4[n].w;
        float num = __builtin_fmaf(bs, fj, nbfi);
        float den = __builtin_fmaf(fi, fj, 1e-8f);
        float l2 = __builtin_fmaf(num, rcpfast(den), s[n][r]);
        s[n][r] = l2;
        pmax = fmaxf(pmax, l2);
      }
    }

    // ---- rare rescale (speculative defer-max)
    if (__any((pmax - m2run) > THR2)) {
      float tm = fmaxf(pmax, __shfl_xor(pmax, 16));
      tm = fmaxf(tm, __shfl_xor(tm, 32));
      float m2n = fmaxf(m2run, tm);
      float alpha = exp2fast(m2run - m2n);
      lsum *= alpha;
      m2run = m2n;
      float af[4];
#pragma unroll
      for (int r = 0; r < 4; ++r) af[r] = __shfl(alpha, lgp * 4 + r);
#pragma unroll
      for (int nd = 0; nd < 4; ++nd)
#pragma unroll
        for (int r = 0; r < 4; ++r) o[nd][r] *= af[r];
    }

    // ---- P = exp2(l2 - m2run), pack bf16, partial row-sum
    u32 w[4][2];
    {
      float ps = 0.f;
#pragma unroll
      for (int n = 0; n < 4; ++n) {
#pragma unroll
        for (int s2 = 0; s2 < 2; ++s2) {
          float p0 = exp2fast(s[n][2 * s2 + 0] - m2run);
          float p1 = exp2fast(s[n][2 * s2 + 1] - m2run);
          ps += p0 + p1;
          w[n][s2] = cvtpk(p0, p1);
        }
      }
      lsum += ps;
    }

    // ---- P -> per-wave LDS (swizzled) -> A-operand frags
    u16* pw = &plds[wid][0];
#pragma unroll
    for (int n = 0; n < 4; ++n) {
      int idx = l15 * 64 + ((n * 16 + lgp * 4) ^ ((l15 & 7) << 3));
      *(u32x2*)(pw + idx) = (u32x2){w[n][0], w[n][1]};
    }
    s16x8 pf[2];
#pragma unroll
    for (int ks = 0; ks < 2; ++ks) {
      int idx = l15 * 64 + ((ks * 32 + lgp * 8) ^ ((l15 & 7) << 3));
      pf[ks] = *(const s16x8*)(pw + idx);
    }

    // ---- PV: o[nd] += P * V
    const u16* vbp = &vbuf[cur][0];
    __builtin_amdgcn_s_setprio(1);
#pragma unroll
    for (int nd = 0; nd < 4; ++nd) {
      s16x8 vf0 = *(const s16x8*)(vbp + nd * 1024 + ofs0);
      s16x8 vf1 = *(const s16x8*)(vbp + nd * 1024 + ofs1);
      o[nd] = __builtin_amdgcn_mfma_f32_16x16x32_bf16(pf[0], vf0, o[nd], 0, 0, 0);
      o[nd] = __builtin_amdgcn_mfma_f32_16x16x32_bf16(pf[1], vf1, o[nd], 0, 0, 0);
    }
    __builtin_amdgcn_s_setprio(0);

    __syncthreads();   // sync2: drains staged gloads, protects vbuf/kbuf
    cur ^= 1;
  }

  // ---- epilogue: reduce lsum across lgp, store (m,l) + unnormalized partial O
  {
    float l = lsum;
    l += __shfl_xor(l, 16);
    l += __shfl_xor(l, 32);
    if (lgp == 0)
      mlz[(bh << 11) + q0 + l15] = make_float2(m2run, l);
#pragma unroll
    for (int nd = 0; nd < 4; ++nd)
#pragma unroll
      for (int r = 0; r < 4; ++r) {
        int q = q0 + lgp * 4 + r;
        opart[((size_t)(b * TSEQ + q)) * D_MODEL + h * HD + nd * 16 + l15] = f2bf(o[nd][r]);
      }
  }
}

// ---------------- combine the 2 kv-splits ----------------
// thread g: row bth = g>>3 (b,t,h), 8 dh elems. out = (o0*a0 + o1*a1) / (l0*a0 + l1*a1)
__global__ __launch_bounds__(256) void attn_combine(const u16* __restrict__ o0,
                                                    const u16* __restrict__ o1,
                                                    const float2* __restrict__ ml,
                                                    u16* __restrict__ aout) {
  int g = blockIdx.x * 256 + threadIdx.x;
  int bth = g >> 3, j0 = (g & 7) * 8;
  int b = bth >> 15, t = (bth >> 4) & 2047, h = bth & 15;
  int mlidx = (((b << 4) | h) << 11) | t;
  float2 v0 = ml[mlidx];
  float2 v1 = ml[NB * NHEAD * TSEQ + mlidx];
  float M = fmaxf(v0.x, v1.x);
  float a0 = exp2fast(v0.x - M), a1 = exp2fast(v1.x - M);
  float rd = __fdividef(1.f, __builtin_fmaf(v0.y, a0, v1.y * a1));
  float s0 = a0 * rd, s1 = a1 * rd;
  size_t base = (size_t)bth * 64 + j0;
  s16x8 x0 = *(const s16x8*)(o0 + base);
  s16x8 x1 = *(const s16x8*)(o1 + base);
  s16x8 out;
#pragma unroll
  for (int j = 0; j < 8; ++j) {
    float f = __builtin_fmaf(bf2f((u16)x0[j]), s0, bf2f((u16)x1[j]) * s1);
    out[j] = (short)f2bf(f);
  }
  *(s16x8*)(aout + base) = out;
}

extern "C" void kernel_launch(void* const* d_in, const int* in_sizes, int n_in,
                              void* d_out, int out_size, void* d_ws, size_t ws_size,
                              hipStream_t stream) {
  const float* query = (const float*)d_in[0];
  const float* key_  = (const float*)d_in[1];
  const float* value = (const float*)d_in[2];
  const float* frac  = (const float*)d_in[3];
  const float* Wq    = (const float*)d_in[4];
  const float* bq    = (const float*)d_in[5];
  const float* Wk    = (const float*)d_in[6];
  const float* bk    = (const float*)d_in[7];
  const float* Wv    = (const float*)d_in[8];
  const float* bv    = (const float*)d_in[9];
  const float* abias = (const float*)d_in[10];
  const float* Wo    = (const float*)d_in[11];
  const float* bo    = (const float*)d_in[12];

  char* ws = (char*)d_ws;
  size_t off = 0;
  auto alloc = [&](size_t bytes) { char* p = ws + off; off += (bytes + 255) & ~255ULL; return p; };
  const size_t XB = (size_t)MROWS * D_MODEL * 2;
  const size_t WB = (size_t)D_MODEL * D_MODEL * 2;
  u16* qb  = (u16*)alloc(XB);
  u16* kb  = (u16*)alloc(XB);
  u16* vb  = (u16*)alloc(XB);
  u16* Wqb = (u16*)alloc(WB);
  u16* Wkb = (u16*)alloc(WB);
  u16* Wvb = (u16*)alloc(WB);
  u16* Wob = (u16*)alloc(WB);
  float* bsum = (float*)alloc(256);
  u16* Qp  = (u16*)alloc(XB);
  u16* Kp  = (u16*)alloc(XB);
  u16* Vtp = (u16*)alloc(XB);
  u16* AO  = (u16*)alloc(XB);

  // kv-split partial buffers reuse regions that are dead after gemm_qkv:
  u16* o0 = qb;                 // 8.39 MB, exactly XB
  u16* o1 = kb;                 // 8.39 MB
  float2* ml = (float2*)vb;     // 1 MB used

  cvt_all<<<dim3(16385), dim3(256), 0, stream>>>(query, key_, value, Wq, Wk, Wv, Wo, abias,
                                                 qb, kb, vb, Wqb, Wkb, Wvb, Wob, bsum);

  gemm_qkv<<<dim3(D_MODEL / 128, MROWS / 128, 3), dim3(256), 0, stream>>>(
      qb, kb, vb, Wqb, Wkb, Wvb, bq, bk, bv, Qp, Kp, Vtp);

  attn_kernel<<<dim3(TSEQ / 64, NB * NHEAD, NSPLIT), dim3(256), 0, stream>>>(
      Qp, Kp, Vtp, frac, bsum, o0, o1, ml);

  attn_combine<<<dim3(MROWS * D_MODEL / 8 / 256), dim3(256), 0, stream>>>(o0, o1, ml, AO);

  gemm_out<<<dim3(D_MODEL / 128, MROWS / 64), dim3(256), 0, stream>>>(AO, Wob, bo, (float*)d_out);
}